// Round 5
// baseline (513.156 us; speedup 1.0000x reference)
//
#include <hip/hip_runtime.h>
#include <cstdint>
#include <cstddef>

#define N_TOK 4096   // 2*2048 tokens
#define DM 1024      // d_model
#define FH 4096      // ffn hidden
#define NE 8         // experts
#define MT_PAD 40    // max M-tiles of 256 across experts (32 + 7 remainders, padded)

typedef __attribute__((ext_vector_type(8))) short short8;  // 8 bf16
typedef __attribute__((ext_vector_type(4))) float f32x4;

#define BAR() asm volatile("s_barrier" ::: "memory")
#define WAITV0() asm volatile("s_waitcnt vmcnt(0)" ::: "memory")

__device__ __forceinline__ unsigned short f2bf(float f) {
  unsigned u = __float_as_uint(f);
  u += 0x7fffu + ((u >> 16) & 1u);   // RNE
  return (unsigned short)(u >> 16);
}

// ---------------- fp32 -> bf16 conversion ----------------
__global__ void cvt_kernel(const float* __restrict__ src, unsigned short* __restrict__ dst, int n4) {
  int stride = gridDim.x * blockDim.x;
  for (int i = blockIdx.x * blockDim.x + threadIdx.x; i < n4; i += stride) {
    float4 v = reinterpret_cast<const float4*>(src)[i];
    ushort4 o;
    o.x = f2bf(v.x); o.y = f2bf(v.y); o.z = f2bf(v.z); o.w = f2bf(v.w);
    reinterpret_cast<ushort4*>(dst)[i] = o;
  }
}

// ---------------- router ----------------
__global__ void router_kernel(const float* __restrict__ x, const float* __restrict__ Wr,
                              float* __restrict__ partials, unsigned char* __restrict__ topidx,
                              float* __restrict__ pslot) {
  __shared__ float sp[NE];
  int lane = threadIdx.x & 63;
  int wv = threadIdx.x >> 6;
  int token = blockIdx.x * 4 + wv;
  if (threadIdx.x < NE) sp[threadIdx.x] = 0.f;
  __syncthreads();

  const float4* xr = (const float4*)(x + (size_t)token * DM);
  float acc[NE];
#pragma unroll
  for (int e = 0; e < NE; e++) acc[e] = 0.f;
#pragma unroll
  for (int d = lane; d < DM / 4; d += 64) {
    float4 xv = xr[d];
#pragma unroll
    for (int e = 0; e < NE; e++) {
      float4 wv4 = ((const float4*)(Wr + e * DM))[d];
      acc[e] += xv.x * wv4.x + xv.y * wv4.y + xv.z * wv4.z + xv.w * wv4.w;
    }
  }
#pragma unroll
  for (int e = 0; e < NE; e++) {
#pragma unroll
    for (int off = 32; off > 0; off >>= 1) acc[e] += __shfl_xor(acc[e], off);
  }
  if (lane == 0) {
    float m = acc[0];
#pragma unroll
    for (int e = 1; e < NE; e++) m = fmaxf(m, acc[e]);
    float p[NE];
    float s = 0.f;
#pragma unroll
    for (int e = 0; e < NE; e++) { p[e] = expf(acc[e] - m); s += p[e]; }
    float inv = 1.f / s;
#pragma unroll
    for (int e = 0; e < NE; e++) p[e] *= inv;
    int i1 = 0;
#pragma unroll
    for (int e = 1; e < NE; e++) if (p[e] > p[i1]) i1 = e;
    int i2 = (i1 == 0) ? 1 : 0;
#pragma unroll
    for (int e = 0; e < NE; e++) if (e != i1 && p[e] > p[i2]) i2 = e;
    float denom = p[i1] + p[i2] + 1e-8f;
    topidx[token] = (unsigned char)(i1 | (i2 << 4));
    pslot[2 * token]     = p[i1] / denom;
    pslot[2 * token + 1] = p[i2] / denom;
#pragma unroll
    for (int e = 0; e < NE; e++) atomicAdd(&sp[e], p[e]);
  }
  __syncthreads();
  if (threadIdx.x < NE) partials[blockIdx.x * NE + threadIdx.x] = sp[threadIdx.x];
}

// ---------------- scatter: wave-aggregated position assignment ----------------
__global__ void scatter_kernel(const unsigned char* __restrict__ topidx,
                               int* __restrict__ counts, int* __restrict__ lists) {
  int token = blockIdx.x * blockDim.x + threadIdx.x;
  int lane = threadIdx.x & 63;
  unsigned char packed = topidx[token];
#pragma unroll
  for (int c = 0; c < 2; c++) {
    int myexp = (c == 0) ? (packed & 15) : (packed >> 4);
    int slot = 2 * token + c;
#pragma unroll
    for (int e = 0; e < NE; e++) {
      unsigned long long mask = __ballot(myexp == e);
      int cnt = __popcll(mask);
      if (cnt) {
        int base = 0;
        if (lane == 0) base = atomicAdd(&counts[e], cnt);
        base = __shfl(base, 0);
        if (myexp == e) {
          int mypos = base + __popcll(mask & ((1ull << lane) - 1ull));
          lists[e * N_TOK + mypos] = slot;
        }
      }
    }
  }
}

// ---------------- tile map (256-row tiles) + prefix ----------------
__global__ void tilemap_kernel(const int* __restrict__ counts, int* __restrict__ prefix,
                               int2* __restrict__ tilemap) {
  if (threadIdx.x != 0) return;
  int off = 0, tix = 0;
  for (int e = 0; e < NE; e++) {
    prefix[e] = off;
    int c = counts[e];
    int ntile = (c + 255) >> 8;
    for (int m = 0; m < ntile; m++) { tilemap[tix].x = e; tilemap[tix].y = m; tix++; }
    off += c;
  }
  prefix[NE] = off;
  while (tix < MT_PAD) { tilemap[tix].x = -1; tilemap[tix].y = 0; tix++; }
}

// ---------------- aux loss ----------------
__global__ void aux_kernel(const float* __restrict__ partials, int nblk,
                           float* __restrict__ aux_out) {
  __shared__ float sp[NE];
  if (threadIdx.x < NE) sp[threadIdx.x] = 0.f;
  __syncthreads();
  float s = 0.f;
  for (int i = threadIdx.x; i < nblk * NE; i += 256) s += partials[i];
  atomicAdd(&sp[threadIdx.x & 7], s);
  __syncthreads();
  if (threadIdx.x == 0) {
    float a = 0.f;
#pragma unroll
    for (int e = 0; e < NE; e++) {
      float tpe = sp[e] * (1.0f / N_TOK);
      float d = tpe - 1.0f / NE;
      a += d * d;
    }
    aux_out[0] = 0.01f * (a * (1.0f / NE));
  }
}

// ---------------- 256x256 2-phase grouped GEMM, double-buffered, counted pipeline ----------------
// Catalog T3-minimum recipe: STAGE(t+1) at top, one vmcnt(0)+s_barrier per K-tile.
// KZ-way K-split (GEMM2): partial results accumulated via fp32 atomicAdd into o2.
// NOTE: ap/bp already include the kz*KC K-split offset; STAGE takes the LOCAL
// K-tile index 0..T-1 (round-4 bug: passing kz*T+t double-counted kz -> OOB -> NaN).
template <int KDIM, int NT, int KZ, bool IS_GEMM1>
__global__ __launch_bounds__(512, 2) void moe_gemm2ph(
    const unsigned short* __restrict__ Aglob,
    const unsigned short* __restrict__ Bglob,
    const int* __restrict__ prefix,
    const int2* __restrict__ tilemap,
    const int* __restrict__ lists,
    const float* __restrict__ pslot,
    unsigned short* __restrict__ hb,
    float* __restrict__ o2) {
  // ---- XCD-chunked bijective decode of 1-D grid (nwg % 8 == 0) ----
  const int NWG = NT * MT_PAD * KZ;
  int wg = blockIdx.x;
  int flat = (wg & 7) * (NWG >> 3) + (wg >> 3);
  int tix = flat % MT_PAD;
  int rest = flat / MT_PAD;
  int nt = rest % NT;
  int kz = rest / NT;

  int2 tm = tilemap[tix];
  if (tm.x < 0) return;
  int e = tm.x, mt = tm.y;
  int base = prefix[e];
  int cnt  = prefix[e + 1] - base;
  if (mt * 256 >= cnt) return;
  const int* list = lists + e * N_TOK;
  const unsigned short* B = Bglob + (size_t)e * (size_t)(NT * 256) * KDIM;

  __shared__ unsigned short As[2 * 16384];  // 2 bufs x 256 rows x 64 cols
  __shared__ unsigned short Bs[2 * 16384];

  int tid = threadIdx.x, wid = tid >> 6, lane = tid & 63;
  int wr = wid >> 2, wc = wid & 3;  // 2 x 4 waves, per-wave output 128x64

  const int KC = KDIM / KZ;   // 1024 both GEMMs
  const int T  = KC / 64;     // 16

  // ---- staging source pointers (pre-swizzled col + kz K-chunk), 4 rounds x (A,B) ----
  int swz = (((lane & 7) ^ (lane >> 3)) << 3);  // elements
  const unsigned short* ap[4];
  const unsigned short* bp[4];
#pragma unroll
  for (int r = 0; r < 4; r++) {
    int row = r * 64 + (tid >> 3);
    int p = mt * 256 + row;
    int pc = p < cnt ? p : cnt - 1;
    int arow = IS_GEMM1 ? (list[pc] >> 1) : (base + pc);
    ap[r] = Aglob + (size_t)arow * KDIM + kz * KC + swz;
    bp[r] = B + (size_t)(nt * 256 + row) * KDIM + kz * KC + swz;
  }

#define STAGE(buf, kt) do { \
    _Pragma("unroll") \
    for (int r = 0; r < 4; r++) { \
      __builtin_amdgcn_global_load_lds((const void*)(ap[r] + (size_t)(kt) * 64), \
          (void*)(&As[(buf) * 16384 + r * 4096 + wid * 512]), 16, 0, 0); \
      __builtin_amdgcn_global_load_lds((const void*)(bp[r] + (size_t)(kt) * 64), \
          (void*)(&Bs[(buf) * 16384 + r * 4096 + wid * 512]), 16, 0, 0); \
    } \
  } while (0)

  f32x4 acc[8][4];
#pragma unroll
  for (int m = 0; m < 8; m++)
#pragma unroll
    for (int n = 0; n < 4; n++) acc[m][n] = (f32x4){0.f, 0.f, 0.f, 0.f};

  // prologue (LOCAL K-tile index 0)
  STAGE(0, 0);
  WAITV0();
  BAR();

  int cur = 0;
  for (int t = 0; t < T; ++t) {
    if (t + 1 < T) STAGE(cur ^ 1, t + 1);

    const char* Ab = (const char*)As + cur * 32768;
    const char* Bb = (const char*)Bs + cur * 32768;
#pragma unroll
    for (int ks = 0; ks < 2; ks++) {
      int cswz = (ks * 64 + ((lane >> 4) << 4)) ^ ((lane & 7) << 4);  // bytes
      short8 bF[4], aF[4];
#pragma unroll
      for (int n = 0; n < 4; n++)
        bF[n] = *(const short8*)(Bb + (wc * 64 + n * 16 + (lane & 15)) * 128 + cswz);
#pragma unroll
      for (int m = 0; m < 4; m++)
        aF[m] = *(const short8*)(Ab + (wr * 128 + m * 16 + (lane & 15)) * 128 + cswz);
      __builtin_amdgcn_s_setprio(1);
#pragma unroll
      for (int m = 0; m < 4; m++)
#pragma unroll
        for (int n = 0; n < 4; n++)
          acc[m][n] = __builtin_amdgcn_mfma_f32_16x16x32_bf16(aF[m], bF[n], acc[m][n], 0, 0, 0);
      __builtin_amdgcn_s_setprio(0);
#pragma unroll
      for (int m = 0; m < 4; m++)
        aF[m] = *(const short8*)(Ab + (wr * 128 + (m + 4) * 16 + (lane & 15)) * 128 + cswz);
      __builtin_amdgcn_s_setprio(1);
#pragma unroll
      for (int m = 0; m < 4; m++)
#pragma unroll
        for (int n = 0; n < 4; n++)
          acc[m + 4][n] = __builtin_amdgcn_mfma_f32_16x16x32_bf16(aF[m], bF[n], acc[m + 4][n], 0, 0, 0);
      __builtin_amdgcn_s_setprio(0);
    }

    if (t + 1 < T) { WAITV0(); BAR(); }
    cur ^= 1;
  }
#undef STAGE

  // ---- epilogue: C/D layout col = lane&15, row = (lane>>4)*4 + reg ----
  int colpart = nt * 256 + wc * 64 + (lane & 15);
#pragma unroll
  for (int m = 0; m < 8; m++) {
#pragma unroll
    for (int rr = 0; rr < 4; rr++) {
      int p = mt * 256 + wr * 128 + m * 16 + (lane >> 4) * 4 + rr;
      if (p < cnt) {
        if (IS_GEMM1) {
          size_t rowbase = (size_t)(base + p) * FH + colpart;
#pragma unroll
          for (int n = 0; n < 4; n++) {
            float v = acc[m][n][rr];
            float g = 0.5f * v * (1.f + erff(v * 0.70710678118654752f));
            hb[rowbase + n * 16] = f2bf(g);
          }
        } else {
          int slot = list[p];
          float sc = pslot[slot];
          size_t rowbase = (size_t)slot * DM + colpart;
#pragma unroll
          for (int n = 0; n < 4; n++) atomicAdd(&o2[rowbase + n * 16], sc * acc[m][n][rr]);
        }
      }
    }
  }
}

// ---------------- combine: out[token] = o2[2t] + o2[2t+1] ----------------
__global__ void combine_kernel(const float* __restrict__ o2, float* __restrict__ out) {
  int idx = blockIdx.x * blockDim.x + threadIdx.x;  // over N_TOK*DM/4
  int token = idx >> 8;                             // DM/4 = 256
  int d4 = idx & 255;
  float4 a = ((const float4*)(o2 + (size_t)(2 * token) * DM))[d4];
  float4 b = ((const float4*)(o2 + (size_t)(2 * token + 1) * DM))[d4];
  float4 s = {a.x + b.x, a.y + b.y, a.z + b.z, a.w + b.w};
  ((float4*)(out + (size_t)token * DM))[d4] = s;
}

extern "C" void kernel_launch(void* const* d_in, const int* in_sizes, int n_in,
                              void* d_out, int out_size, void* d_ws, size_t ws_size,
                              hipStream_t stream) {
  const float* x  = (const float*)d_in[0];
  const float* Wr = (const float*)d_in[1];
  const float* W1 = (const float*)d_in[2];
  const float* W2 = (const float*)d_in[3];
  float* out = (float*)d_out;

  char* ws = (char*)d_ws;
  int*   counts   = (int*)(ws + 0);                    // 32 B
  int*   prefix   = (int*)(ws + 64);                   // 36 B
  unsigned char* topidx = (unsigned char*)(ws + 128);  // 4096 B
  int2*  tilemap  = (int2*)(ws + 4352);                // 320 B
  float* pslot    = (float*)(ws + 8192);               // 32 KB
  float* partials = (float*)(ws + 40960);              // 32 KB
  int*   lists    = (int*)(ws + 73728);                // 128 KB -> ends 204800
  unsigned short* xb  = (unsigned short*)(ws + 204800);                               // 8 MiB
  unsigned short* w1b = (unsigned short*)(ws + 204800 + 8388608);                     // 64 MiB
  unsigned short* w2b = (unsigned short*)(ws + 204800 + 8388608 + 67108864);          // 64 MiB
  unsigned short* hb  = (unsigned short*)(ws + 204800 + 8388608 + 2ull * 67108864);   // 64 MiB
  float*          o2  = (float*)(ws + 204800 + 8388608 + 3ull * 67108864);            // 32 MiB
  (void)in_sizes; (void)n_in; (void)ws_size;

  hipMemsetAsync(counts, 0, 32, stream);
  hipMemsetAsync(o2, 0, (size_t)2 * N_TOK * DM * sizeof(float), stream);

  cvt_kernel<<<2048, 256, 0, stream>>>(x,  xb,  N_TOK * DM / 4);
  cvt_kernel<<<2048, 256, 0, stream>>>(W1, w1b, NE * FH * DM / 4);
  cvt_kernel<<<2048, 256, 0, stream>>>(W2, w2b, NE * DM * FH / 4);

  router_kernel<<<N_TOK / 4, 256, 0, stream>>>(x, Wr, partials, topidx, pslot);
  scatter_kernel<<<N_TOK / 256, 256, 0, stream>>>(topidx, counts, lists);
  tilemap_kernel<<<1, 64, 0, stream>>>(counts, prefix, tilemap);
  aux_kernel<<<1, 256, 0, stream>>>(partials, N_TOK / 4, out + (size_t)N_TOK * DM);

  // GEMM1: N=FH(4096), K=DM(1024), KZ=1; writes hb compact (gelu, bf16). 16*40 = 640 blocks.
  moe_gemm2ph<DM, FH / 256, 1, true><<<(FH / 256) * MT_PAD, 512, 0, stream>>>(
      xb, w1b, prefix, tilemap, lists, pslot, hb, nullptr);
  // GEMM2: N=DM(1024), K=FH(4096), KZ=4 K-split; atomicAdd into o2. 4*40*4 = 640 blocks.
  moe_gemm2ph<FH, DM / 256, 4, false><<<(DM / 256) * MT_PAD * 4, 512, 0, stream>>>(
      hb, w2b, prefix, tilemap, lists, pslot, nullptr, o2);

  combine_kernel<<<N_TOK * DM / 4 / 256, 256, 0, stream>>>(o2, out);
}

// Round 6
// 355.296 us; speedup vs baseline: 1.4443x; 1.4443x over previous
//
#include <hip/hip_runtime.h>
#include <cstdint>
#include <cstddef>

#define N_TOK 4096   // 2*2048 tokens
#define DM 1024      // d_model
#define FH 4096      // ffn hidden
#define NE 8         // experts
#define MT_PAD 72    // max 128-row M-tiles across experts (64 + 7 remainders, padded to /8)

typedef __attribute__((ext_vector_type(8))) short short8;  // 8 bf16
typedef __attribute__((ext_vector_type(4))) float f32x4;

#define WAITV0() asm volatile("s_waitcnt vmcnt(0)" ::: "memory")

__device__ __forceinline__ unsigned short f2bf(float f) {
  unsigned u = __float_as_uint(f);
  u += 0x7fffu + ((u >> 16) & 1u);   // RNE
  return (unsigned short)(u >> 16);
}

// ---------------- fp32 -> bf16 conversion ----------------
__global__ void cvt_kernel(const float* __restrict__ src, unsigned short* __restrict__ dst, int n4) {
  int stride = gridDim.x * blockDim.x;
  for (int i = blockIdx.x * blockDim.x + threadIdx.x; i < n4; i += stride) {
    float4 v = reinterpret_cast<const float4*>(src)[i];
    ushort4 o;
    o.x = f2bf(v.x); o.y = f2bf(v.y); o.z = f2bf(v.z); o.w = f2bf(v.w);
    reinterpret_cast<ushort4*>(dst)[i] = o;
  }
}

// ---------------- router ----------------
__global__ void router_kernel(const float* __restrict__ x, const float* __restrict__ Wr,
                              float* __restrict__ partials, unsigned char* __restrict__ topidx,
                              float* __restrict__ pslot) {
  __shared__ float sp[NE];
  int lane = threadIdx.x & 63;
  int wv = threadIdx.x >> 6;
  int token = blockIdx.x * 4 + wv;
  if (threadIdx.x < NE) sp[threadIdx.x] = 0.f;
  __syncthreads();

  const float4* xr = (const float4*)(x + (size_t)token * DM);
  float acc[NE];
#pragma unroll
  for (int e = 0; e < NE; e++) acc[e] = 0.f;
#pragma unroll
  for (int d = lane; d < DM / 4; d += 64) {
    float4 xv = xr[d];
#pragma unroll
    for (int e = 0; e < NE; e++) {
      float4 wv4 = ((const float4*)(Wr + e * DM))[d];
      acc[e] += xv.x * wv4.x + xv.y * wv4.y + xv.z * wv4.z + xv.w * wv4.w;
    }
  }
#pragma unroll
  for (int e = 0; e < NE; e++) {
#pragma unroll
    for (int off = 32; off > 0; off >>= 1) acc[e] += __shfl_xor(acc[e], off);
  }
  if (lane == 0) {
    float m = acc[0];
#pragma unroll
    for (int e = 1; e < NE; e++) m = fmaxf(m, acc[e]);
    float p[NE];
    float s = 0.f;
#pragma unroll
    for (int e = 0; e < NE; e++) { p[e] = expf(acc[e] - m); s += p[e]; }
    float inv = 1.f / s;
#pragma unroll
    for (int e = 0; e < NE; e++) p[e] *= inv;
    int i1 = 0;
#pragma unroll
    for (int e = 1; e < NE; e++) if (p[e] > p[i1]) i1 = e;
    int i2 = (i1 == 0) ? 1 : 0;
#pragma unroll
    for (int e = 0; e < NE; e++) if (e != i1 && p[e] > p[i2]) i2 = e;
    float denom = p[i1] + p[i2] + 1e-8f;
    topidx[token] = (unsigned char)(i1 | (i2 << 4));
    pslot[2 * token]     = p[i1] / denom;
    pslot[2 * token + 1] = p[i2] / denom;
#pragma unroll
    for (int e = 0; e < NE; e++) atomicAdd(&sp[e], p[e]);
  }
  __syncthreads();
  if (threadIdx.x < NE) partials[blockIdx.x * NE + threadIdx.x] = sp[threadIdx.x];
}

// ---------------- scatter: wave-aggregated position assignment ----------------
__global__ void scatter_kernel(const unsigned char* __restrict__ topidx,
                               int* __restrict__ counts, int* __restrict__ lists) {
  int token = blockIdx.x * blockDim.x + threadIdx.x;
  int lane = threadIdx.x & 63;
  unsigned char packed = topidx[token];
#pragma unroll
  for (int c = 0; c < 2; c++) {
    int myexp = (c == 0) ? (packed & 15) : (packed >> 4);
    int slot = 2 * token + c;
#pragma unroll
    for (int e = 0; e < NE; e++) {
      unsigned long long mask = __ballot(myexp == e);
      int cnt = __popcll(mask);
      if (cnt) {
        int base = 0;
        if (lane == 0) base = atomicAdd(&counts[e], cnt);
        base = __shfl(base, 0);
        if (myexp == e) {
          int mypos = base + __popcll(mask & ((1ull << lane) - 1ull));
          lists[e * N_TOK + mypos] = slot;
        }
      }
    }
  }
}

// ---------------- tile map (128-row tiles) + prefix ----------------
__global__ void tilemap_kernel(const int* __restrict__ counts, int* __restrict__ prefix,
                               int2* __restrict__ tilemap) {
  if (threadIdx.x != 0) return;
  int off = 0, tix = 0;
  for (int e = 0; e < NE; e++) {
    prefix[e] = off;
    int c = counts[e];
    int ntile = (c + 127) >> 7;
    for (int m = 0; m < ntile; m++) { tilemap[tix].x = e; tilemap[tix].y = m; tix++; }
    off += c;
  }
  prefix[NE] = off;
  while (tix < MT_PAD) { tilemap[tix].x = -1; tilemap[tix].y = 0; tix++; }
}

// ---------------- aux loss ----------------
__global__ void aux_kernel(const float* __restrict__ partials, int nblk,
                           float* __restrict__ aux_out) {
  __shared__ float sp[NE];
  if (threadIdx.x < NE) sp[threadIdx.x] = 0.f;
  __syncthreads();
  float s = 0.f;
  for (int i = threadIdx.x; i < nblk * NE; i += 256) s += partials[i];
  atomicAdd(&sp[threadIdx.x & 7], s);
  __syncthreads();
  if (threadIdx.x == 0) {
    float a = 0.f;
#pragma unroll
    for (int e = 0; e < NE; e++) {
      float tpe = sp[e] * (1.0f / N_TOK);
      float d = tpe - 1.0f / NE;
      a += d * d;
    }
    aux_out[0] = 0.01f * (a * (1.0f / NE));
  }
}

// ---------------- 128x128 grouped GEMM, m97 structure + XOR swizzle ----------------
// 256 threads / 4 waves (2x2 of 64x64), BK=64, 32 KiB LDS (single-buffered),
// 2 barriers per K-tile; relies on ~3-4 blocks/CU for implicit overlap (m97: 912 TF).
// Swizzle: LDS dest linear; source col pre-swizzled; ds_read applies same XOR.
template <int KDIM, int NT, bool IS_GEMM1>
__global__ __launch_bounds__(256) void moe_gemm128(
    const unsigned short* __restrict__ Aglob,
    const unsigned short* __restrict__ Bglob,
    const int* __restrict__ prefix,
    const int2* __restrict__ tilemap,
    const int* __restrict__ lists,
    const float* __restrict__ pslot,
    unsigned short* __restrict__ hb,
    float* __restrict__ o2) {
  // ---- XCD-chunked bijective decode (nwg % 8 == 0); consecutive flat share nt (B panel) ----
  const int NWG = NT * MT_PAD;
  int wg = blockIdx.x;
  int flat = (wg & 7) * (NWG >> 3) + (wg >> 3);
  int tix = flat % MT_PAD;
  int nt = flat / MT_PAD;

  int2 tm = tilemap[tix];
  if (tm.x < 0) return;
  int e = tm.x, mt = tm.y;
  int base = prefix[e];
  int cnt  = prefix[e + 1] - base;
  const int* list = lists + e * N_TOK;
  const unsigned short* B = Bglob + (size_t)e * (size_t)(NT * 128) * KDIM;

  __shared__ unsigned short As[128 * 64];
  __shared__ unsigned short Bs[128 * 64];

  int tid = threadIdx.x, wid = tid >> 6, lane = tid & 63;
  int wr = wid >> 1, wc = wid & 1;  // 2x2 waves, each 64x64 output

  // ---- staging sources: 16 chunks of 8 rows; lane covers row (lane>>3), unit (lane&7) ----
  int swz = (((lane & 7) ^ (lane >> 3)) << 3);  // pre-swizzled col in elements
  const unsigned short* ap[4];
  const unsigned short* bp[4];
#pragma unroll
  for (int i = 0; i < 4; i++) {
    int c = i * 4 + wid;
    int r = c * 8 + (lane >> 3);  // tile row 0..127
    int p = mt * 128 + r;
    int pc = p < cnt ? p : cnt - 1;
    int arow = IS_GEMM1 ? (list[pc] >> 1) : (base + pc);
    ap[i] = Aglob + (size_t)arow * KDIM + swz;
    bp[i] = B + (size_t)(nt * 128 + r) * KDIM + swz;
  }

  f32x4 acc[4][4];
#pragma unroll
  for (int m = 0; m < 4; m++)
#pragma unroll
    for (int n = 0; n < 4; n++) acc[m][n] = (f32x4){0.f, 0.f, 0.f, 0.f};

  const int T = KDIM / 64;
  for (int t = 0; t < T; ++t) {
    if (t > 0) __syncthreads();  // previous tile's reads done before overwrite
#pragma unroll
    for (int i = 0; i < 4; i++) {
      int c = i * 4 + wid;
      __builtin_amdgcn_global_load_lds((const void*)(ap[i] + (size_t)t * 64),
                                       (void*)(&As[c * 512]), 16, 0, 0);
      __builtin_amdgcn_global_load_lds((const void*)(bp[i] + (size_t)t * 64),
                                       (void*)(&Bs[c * 512]), 16, 0, 0);
    }
    WAITV0();
    __syncthreads();
#pragma unroll
    for (int ks = 0; ks < 2; ks++) {
      short8 aF[4], bF[4];
#pragma unroll
      for (int m = 0; m < 4; m++) {
        int row = wr * 64 + m * 16 + (lane & 15);
        int cswz = (ks * 64 + ((lane >> 4) << 4)) ^ ((row & 7) << 4);  // bytes
        aF[m] = *(const short8*)((const char*)As + row * 128 + cswz);
      }
#pragma unroll
      for (int n = 0; n < 4; n++) {
        int row = wc * 64 + n * 16 + (lane & 15);
        int cswz = (ks * 64 + ((lane >> 4) << 4)) ^ ((row & 7) << 4);
        bF[n] = *(const short8*)((const char*)Bs + row * 128 + cswz);
      }
      __builtin_amdgcn_s_setprio(1);
#pragma unroll
      for (int m = 0; m < 4; m++)
#pragma unroll
        for (int n = 0; n < 4; n++)
          acc[m][n] = __builtin_amdgcn_mfma_f32_16x16x32_bf16(aF[m], bF[n], acc[m][n], 0, 0, 0);
      __builtin_amdgcn_s_setprio(0);
    }
  }

  // ---- epilogue: C/D layout col = lane&15, row = (lane>>4)*4 + reg ----
  int colpart = nt * 128 + wc * 64 + (lane & 15);
#pragma unroll
  for (int m = 0; m < 4; m++) {
#pragma unroll
    for (int rr = 0; rr < 4; rr++) {
      int p = mt * 128 + wr * 64 + m * 16 + (lane >> 4) * 4 + rr;
      if (p < cnt) {
        if (IS_GEMM1) {
          size_t rowbase = (size_t)(base + p) * FH + colpart;
#pragma unroll
          for (int n = 0; n < 4; n++) {
            float v = acc[m][n][rr];
            float g = 0.5f * v * (1.f + erff(v * 0.70710678118654752f));
            hb[rowbase + n * 16] = f2bf(g);
          }
        } else {
          int slot = list[p];
          float sc = pslot[slot];
          size_t rowbase = (size_t)slot * DM + colpart;
#pragma unroll
          for (int n = 0; n < 4; n++) o2[rowbase + n * 16] = sc * acc[m][n][rr];
        }
      }
    }
  }
}

// ---------------- combine: out[token] = o2[2t] + o2[2t+1] ----------------
__global__ void combine_kernel(const float* __restrict__ o2, float* __restrict__ out) {
  int idx = blockIdx.x * blockDim.x + threadIdx.x;  // over N_TOK*DM/4
  int token = idx >> 8;                             // DM/4 = 256
  int d4 = idx & 255;
  float4 a = ((const float4*)(o2 + (size_t)(2 * token) * DM))[d4];
  float4 b = ((const float4*)(o2 + (size_t)(2 * token + 1) * DM))[d4];
  float4 s = {a.x + b.x, a.y + b.y, a.z + b.z, a.w + b.w};
  ((float4*)(out + (size_t)token * DM))[d4] = s;
}

extern "C" void kernel_launch(void* const* d_in, const int* in_sizes, int n_in,
                              void* d_out, int out_size, void* d_ws, size_t ws_size,
                              hipStream_t stream) {
  const float* x  = (const float*)d_in[0];
  const float* Wr = (const float*)d_in[1];
  const float* W1 = (const float*)d_in[2];
  const float* W2 = (const float*)d_in[3];
  float* out = (float*)d_out;

  char* ws = (char*)d_ws;
  int*   counts   = (int*)(ws + 0);                    // 32 B
  int*   prefix   = (int*)(ws + 64);                   // 36 B
  unsigned char* topidx = (unsigned char*)(ws + 128);  // 4096 B
  int2*  tilemap  = (int2*)(ws + 4352);                // 576 B
  float* pslot    = (float*)(ws + 8192);               // 32 KB
  float* partials = (float*)(ws + 40960);              // 32 KB
  int*   lists    = (int*)(ws + 73728);                // 128 KB -> ends 204800
  unsigned short* xb  = (unsigned short*)(ws + 204800);                               // 8 MiB
  unsigned short* w1b = (unsigned short*)(ws + 204800 + 8388608);                     // 64 MiB
  unsigned short* w2b = (unsigned short*)(ws + 204800 + 8388608 + 67108864);          // 64 MiB
  unsigned short* hb  = (unsigned short*)(ws + 204800 + 8388608 + 2ull * 67108864);   // 64 MiB
  float*          o2  = (float*)(ws + 204800 + 8388608 + 3ull * 67108864);            // 32 MiB
  (void)in_sizes; (void)n_in; (void)ws_size;

  hipMemsetAsync(counts, 0, 32, stream);

  cvt_kernel<<<2048, 256, 0, stream>>>(x,  xb,  N_TOK * DM / 4);
  cvt_kernel<<<2048, 256, 0, stream>>>(W1, w1b, NE * FH * DM / 4);
  cvt_kernel<<<2048, 256, 0, stream>>>(W2, w2b, NE * DM * FH / 4);

  router_kernel<<<N_TOK / 4, 256, 0, stream>>>(x, Wr, partials, topidx, pslot);
  scatter_kernel<<<N_TOK / 256, 256, 0, stream>>>(topidx, counts, lists);
  tilemap_kernel<<<1, 64, 0, stream>>>(counts, prefix, tilemap);
  aux_kernel<<<1, 256, 0, stream>>>(partials, N_TOK / 4, out + (size_t)N_TOK * DM);

  // GEMM1: N=FH(4096), K=DM(1024); writes hb compact (gelu, bf16). 32*72 = 2304 blocks.
  moe_gemm128<DM, FH / 128, true><<<(FH / 128) * MT_PAD, 256, 0, stream>>>(
      xb, w1b, prefix, tilemap, lists, pslot, hb, nullptr);
  // GEMM2: N=DM(1024), K=FH(4096); reads hb contiguous, plain stores to o2. 8*72 = 576 blocks.
  moe_gemm128<FH, DM / 128, false><<<(DM / 128) * MT_PAD, 256, 0, stream>>>(
      hb, w2b, prefix, tilemap, lists, pslot, nullptr, o2);

  combine_kernel<<<N_TOK * DM / 4 / 256, 256, 0, stream>>>(o2, out);
}

// Round 7
// 315.787 us; speedup vs baseline: 1.6250x; 1.1251x over previous
//
#include <hip/hip_runtime.h>
#include <cstdint>
#include <cstddef>

#define N_TOK 4096   // 2*2048 tokens
#define DM 1024      // d_model
#define FH 4096      // ffn hidden
#define NE 8         // experts
#define MT_PAD 72    // max 128-row M-tiles across experts (64 + 7 remainders, padded to /8)

typedef __attribute__((ext_vector_type(8))) short short8;  // 8 bf16
typedef __attribute__((ext_vector_type(4))) float f32x4;

#define WAITV0() asm volatile("s_waitcnt vmcnt(0)" ::: "memory")

__device__ __forceinline__ unsigned short f2bf(float f) {
  unsigned u = __float_as_uint(f);
  u += 0x7fffu + ((u >> 16) & 1u);   // RNE
  return (unsigned short)(u >> 16);
}

// tanh-form GELU: g = x·e/(1+e), e = exp(1.5957692·x·(1+0.044715x²))
// max |err| vs erf-GELU ~1e-3; one v_exp + one v_rcp instead of erff's ~40 VALU ops
__device__ __forceinline__ float gelu_fast(float v) {
  float e = __expf(1.5957692f * v * fmaf(0.044715f, v * v, 1.0f));
  return v - v * __builtin_amdgcn_rcpf(1.0f + e);
}

// ---------------- fp32 -> bf16 conversion ----------------
__global__ void cvt_kernel(const float* __restrict__ src, unsigned short* __restrict__ dst, int n4) {
  int stride = gridDim.x * blockDim.x;
  for (int i = blockIdx.x * blockDim.x + threadIdx.x; i < n4; i += stride) {
    float4 v = reinterpret_cast<const float4*>(src)[i];
    ushort4 o;
    o.x = f2bf(v.x); o.y = f2bf(v.y); o.z = f2bf(v.z); o.w = f2bf(v.w);
    reinterpret_cast<ushort4*>(dst)[i] = o;
  }
}

// ---------------- router (fused x -> bf16 cvt) ----------------
__global__ void router_kernel(const float* __restrict__ x, const float* __restrict__ Wr,
                              float* __restrict__ partials, unsigned char* __restrict__ topidx,
                              float* __restrict__ pslot, unsigned short* __restrict__ xb) {
  __shared__ float sp[NE];
  int lane = threadIdx.x & 63;
  int wv = threadIdx.x >> 6;
  int token = blockIdx.x * 4 + wv;
  if (threadIdx.x < NE) sp[threadIdx.x] = 0.f;
  __syncthreads();

  const float4* xr = (const float4*)(x + (size_t)token * DM);
  ushort4* xw = (ushort4*)(xb + (size_t)token * DM);
  float acc[NE];
#pragma unroll
  for (int e = 0; e < NE; e++) acc[e] = 0.f;
#pragma unroll
  for (int d = lane; d < DM / 4; d += 64) {
    float4 xv = xr[d];
    ushort4 o;
    o.x = f2bf(xv.x); o.y = f2bf(xv.y); o.z = f2bf(xv.z); o.w = f2bf(xv.w);
    xw[d] = o;
#pragma unroll
    for (int e = 0; e < NE; e++) {
      float4 wv4 = ((const float4*)(Wr + e * DM))[d];
      acc[e] += xv.x * wv4.x + xv.y * wv4.y + xv.z * wv4.z + xv.w * wv4.w;
    }
  }
#pragma unroll
  for (int e = 0; e < NE; e++) {
#pragma unroll
    for (int off = 32; off > 0; off >>= 1) acc[e] += __shfl_xor(acc[e], off);
  }
  if (lane == 0) {
    float m = acc[0];
#pragma unroll
    for (int e = 1; e < NE; e++) m = fmaxf(m, acc[e]);
    float p[NE];
    float s = 0.f;
#pragma unroll
    for (int e = 0; e < NE; e++) { p[e] = expf(acc[e] - m); s += p[e]; }
    float inv = 1.f / s;
#pragma unroll
    for (int e = 0; e < NE; e++) p[e] *= inv;
    int i1 = 0;
#pragma unroll
    for (int e = 1; e < NE; e++) if (p[e] > p[i1]) i1 = e;
    int i2 = (i1 == 0) ? 1 : 0;
#pragma unroll
    for (int e = 0; e < NE; e++) if (e != i1 && p[e] > p[i2]) i2 = e;
    float denom = p[i1] + p[i2] + 1e-8f;
    topidx[token] = (unsigned char)(i1 | (i2 << 4));
    pslot[2 * token]     = p[i1] / denom;
    pslot[2 * token + 1] = p[i2] / denom;
#pragma unroll
    for (int e = 0; e < NE; e++) atomicAdd(&sp[e], p[e]);
  }
  __syncthreads();
  if (threadIdx.x < NE) partials[blockIdx.x * NE + threadIdx.x] = sp[threadIdx.x];
}

// ---------------- scatter: wave-aggregated position assignment ----------------
__global__ void scatter_kernel(const unsigned char* __restrict__ topidx,
                               int* __restrict__ counts, int* __restrict__ lists) {
  int token = blockIdx.x * blockDim.x + threadIdx.x;
  int lane = threadIdx.x & 63;
  unsigned char packed = topidx[token];
#pragma unroll
  for (int c = 0; c < 2; c++) {
    int myexp = (c == 0) ? (packed & 15) : (packed >> 4);
    int slot = 2 * token + c;
#pragma unroll
    for (int e = 0; e < NE; e++) {
      unsigned long long mask = __ballot(myexp == e);
      int cnt = __popcll(mask);
      if (cnt) {
        int base = 0;
        if (lane == 0) base = atomicAdd(&counts[e], cnt);
        base = __shfl(base, 0);
        if (myexp == e) {
          int mypos = base + __popcll(mask & ((1ull << lane) - 1ull));
          lists[e * N_TOK + mypos] = slot;
        }
      }
    }
  }
}

// ---------------- tile map (128-row tiles) + prefix ----------------
__global__ void tilemap_kernel(const int* __restrict__ counts, int* __restrict__ prefix,
                               int2* __restrict__ tilemap) {
  if (threadIdx.x != 0) return;
  int off = 0, tix = 0;
  for (int e = 0; e < NE; e++) {
    prefix[e] = off;
    int c = counts[e];
    int ntile = (c + 127) >> 7;
    for (int m = 0; m < ntile; m++) { tilemap[tix].x = e; tilemap[tix].y = m; tix++; }
    off += c;
  }
  prefix[NE] = off;
  while (tix < MT_PAD) { tilemap[tix].x = -1; tilemap[tix].y = 0; tix++; }
}

// ---------------- aux loss ----------------
__global__ void aux_kernel(const float* __restrict__ partials, int nblk,
                           float* __restrict__ aux_out) {
  __shared__ float sp[NE];
  if (threadIdx.x < NE) sp[threadIdx.x] = 0.f;
  __syncthreads();
  float s = 0.f;
  for (int i = threadIdx.x; i < nblk * NE; i += 256) s += partials[i];
  atomicAdd(&sp[threadIdx.x & 7], s);
  __syncthreads();
  if (threadIdx.x == 0) {
    float a = 0.f;
#pragma unroll
    for (int e = 0; e < NE; e++) {
      float tpe = sp[e] * (1.0f / N_TOK);
      float d = tpe - 1.0f / NE;
      a += d * d;
    }
    aux_out[0] = 0.01f * (a * (1.0f / NE));
  }
}

// ---------------- 128x128 grouped GEMM, m97 structure + XOR swizzle ----------------
// 256 threads / 4 waves (2x2 of 64x64), BK=64, 32 KiB LDS, 2 barriers per K-tile.
// Grid decode: nt-FAST within each XCD chunk -> one A-tile stays L2-hot across
// its NT column-blocks; B (<=8MB/expert) re-served by LLC. (Round-6 tix-fast
// order streamed A NT times: GEMM2 FETCH 306MB vs ~130MB unique.)
template <int KDIM, int NT, bool IS_GEMM1>
__global__ __launch_bounds__(256) void moe_gemm128(
    const unsigned short* __restrict__ Aglob,
    const unsigned short* __restrict__ Bglob,
    const int* __restrict__ prefix,
    const int2* __restrict__ tilemap,
    const int* __restrict__ lists,
    const float* __restrict__ pslot,
    unsigned short* __restrict__ hb,
    float* __restrict__ o2) {
  const int NWG = NT * MT_PAD;
  int wg = blockIdx.x;
  int flat = (wg & 7) * (NWG >> 3) + (wg >> 3);
  int nt = flat % NT;          // fast: same tix across consecutive blocks
  int tix = flat / NT;

  int2 tm = tilemap[tix];
  if (tm.x < 0) return;
  int e = tm.x, mt = tm.y;
  int base = prefix[e];
  int cnt  = prefix[e + 1] - base;
  const int* list = lists + e * N_TOK;
  const unsigned short* B = Bglob + (size_t)e * (size_t)(NT * 128) * KDIM;

  __shared__ unsigned short As[128 * 64];
  __shared__ unsigned short Bs[128 * 64];

  int tid = threadIdx.x, wid = tid >> 6, lane = tid & 63;
  int wr = wid >> 1, wc = wid & 1;  // 2x2 waves, each 64x64 output

  // ---- staging sources: 16 chunks of 8 rows; lane covers row (lane>>3), unit (lane&7) ----
  int swz = (((lane & 7) ^ (lane >> 3)) << 3);  // pre-swizzled col in elements
  const unsigned short* ap[4];
  const unsigned short* bp[4];
#pragma unroll
  for (int i = 0; i < 4; i++) {
    int c = i * 4 + wid;
    int r = c * 8 + (lane >> 3);  // tile row 0..127
    int p = mt * 128 + r;
    int pc = p < cnt ? p : cnt - 1;
    int arow = IS_GEMM1 ? (list[pc] >> 1) : (base + pc);
    ap[i] = Aglob + (size_t)arow * KDIM + swz;
    bp[i] = B + (size_t)(nt * 128 + r) * KDIM + swz;
  }

  f32x4 acc[4][4];
#pragma unroll
  for (int m = 0; m < 4; m++)
#pragma unroll
    for (int n = 0; n < 4; n++) acc[m][n] = (f32x4){0.f, 0.f, 0.f, 0.f};

  const int T = KDIM / 64;
  for (int t = 0; t < T; ++t) {
    if (t > 0) __syncthreads();  // previous tile's reads done before overwrite
#pragma unroll
    for (int i = 0; i < 4; i++) {
      int c = i * 4 + wid;
      __builtin_amdgcn_global_load_lds((const void*)(ap[i] + (size_t)t * 64),
                                       (void*)(&As[c * 512]), 16, 0, 0);
      __builtin_amdgcn_global_load_lds((const void*)(bp[i] + (size_t)t * 64),
                                       (void*)(&Bs[c * 512]), 16, 0, 0);
    }
    WAITV0();
    __syncthreads();
#pragma unroll
    for (int ks = 0; ks < 2; ks++) {
      short8 aF[4], bF[4];
#pragma unroll
      for (int m = 0; m < 4; m++) {
        int row = wr * 64 + m * 16 + (lane & 15);
        int cswz = (ks * 64 + ((lane >> 4) << 4)) ^ ((row & 7) << 4);  // bytes
        aF[m] = *(const short8*)((const char*)As + row * 128 + cswz);
      }
#pragma unroll
      for (int n = 0; n < 4; n++) {
        int row = wc * 64 + n * 16 + (lane & 15);
        int cswz = (ks * 64 + ((lane >> 4) << 4)) ^ ((row & 7) << 4);
        bF[n] = *(const short8*)((const char*)Bs + row * 128 + cswz);
      }
      __builtin_amdgcn_s_setprio(1);
#pragma unroll
      for (int m = 0; m < 4; m++)
#pragma unroll
        for (int n = 0; n < 4; n++)
          acc[m][n] = __builtin_amdgcn_mfma_f32_16x16x32_bf16(aF[m], bF[n], acc[m][n], 0, 0, 0);
      __builtin_amdgcn_s_setprio(0);
    }
  }

  // ---- epilogue: C/D layout col = lane&15, row = (lane>>4)*4 + reg ----
  int colpart = nt * 128 + wc * 64 + (lane & 15);
#pragma unroll
  for (int m = 0; m < 4; m++) {
#pragma unroll
    for (int rr = 0; rr < 4; rr++) {
      int p = mt * 128 + wr * 64 + m * 16 + (lane >> 4) * 4 + rr;
      if (p < cnt) {
        if (IS_GEMM1) {
          size_t rowbase = (size_t)(base + p) * FH + colpart;
#pragma unroll
          for (int n = 0; n < 4; n++)
            hb[rowbase + n * 16] = f2bf(gelu_fast(acc[m][n][rr]));
        } else {
          int slot = list[p];
          float sc = pslot[slot];
          size_t rowbase = (size_t)slot * DM + colpart;
#pragma unroll
          for (int n = 0; n < 4; n++) o2[rowbase + n * 16] = sc * acc[m][n][rr];
        }
      }
    }
  }
}

// ---------------- combine: out[token] = o2[2t] + o2[2t+1] ----------------
__global__ void combine_kernel(const float* __restrict__ o2, float* __restrict__ out) {
  int idx = blockIdx.x * blockDim.x + threadIdx.x;  // over N_TOK*DM/4
  int token = idx >> 8;                             // DM/4 = 256
  int d4 = idx & 255;
  float4 a = ((const float4*)(o2 + (size_t)(2 * token) * DM))[d4];
  float4 b = ((const float4*)(o2 + (size_t)(2 * token + 1) * DM))[d4];
  float4 s = {a.x + b.x, a.y + b.y, a.z + b.z, a.w + b.w};
  ((float4*)(out + (size_t)token * DM))[d4] = s;
}

extern "C" void kernel_launch(void* const* d_in, const int* in_sizes, int n_in,
                              void* d_out, int out_size, void* d_ws, size_t ws_size,
                              hipStream_t stream) {
  const float* x  = (const float*)d_in[0];
  const float* Wr = (const float*)d_in[1];
  const float* W1 = (const float*)d_in[2];
  const float* W2 = (const float*)d_in[3];
  float* out = (float*)d_out;

  char* ws = (char*)d_ws;
  int*   counts   = (int*)(ws + 0);                    // 32 B
  int*   prefix   = (int*)(ws + 64);                   // 36 B
  unsigned char* topidx = (unsigned char*)(ws + 128);  // 4096 B
  int2*  tilemap  = (int2*)(ws + 4352);                // 576 B
  float* pslot    = (float*)(ws + 8192);               // 32 KB
  float* partials = (float*)(ws + 40960);              // 32 KB
  int*   lists    = (int*)(ws + 73728);                // 128 KB -> ends 204800
  unsigned short* xb  = (unsigned short*)(ws + 204800);                               // 8 MiB
  unsigned short* w1b = (unsigned short*)(ws + 204800 + 8388608);                     // 64 MiB
  unsigned short* w2b = (unsigned short*)(ws + 204800 + 8388608 + 67108864);          // 64 MiB
  unsigned short* hb  = (unsigned short*)(ws + 204800 + 8388608 + 2ull * 67108864);   // 64 MiB
  float*          o2  = (float*)(ws + 204800 + 8388608 + 3ull * 67108864);            // 32 MiB
  (void)in_sizes; (void)n_in; (void)ws_size;

  hipMemsetAsync(counts, 0, 32, stream);

  cvt_kernel<<<2048, 256, 0, stream>>>(W1, w1b, NE * FH * DM / 4);
  cvt_kernel<<<2048, 256, 0, stream>>>(W2, w2b, NE * DM * FH / 4);

  router_kernel<<<N_TOK / 4, 256, 0, stream>>>(x, Wr, partials, topidx, pslot, xb);
  scatter_kernel<<<N_TOK / 256, 256, 0, stream>>>(topidx, counts, lists);
  tilemap_kernel<<<1, 64, 0, stream>>>(counts, prefix, tilemap);
  aux_kernel<<<1, 256, 0, stream>>>(partials, N_TOK / 4, out + (size_t)N_TOK * DM);

  // GEMM1: N=FH(4096), K=DM(1024); writes hb compact (gelu, bf16). 32*72 = 2304 blocks.
  moe_gemm128<DM, FH / 128, true><<<(FH / 128) * MT_PAD, 256, 0, stream>>>(
      xb, w1b, prefix, tilemap, lists, pslot, hb, nullptr);
  // GEMM2: N=DM(1024), K=FH(4096); reads hb contiguous, plain stores to o2. 8*72 = 576 blocks.
  moe_gemm128<FH, DM / 128, false><<<(DM / 128) * MT_PAD, 256, 0, stream>>>(
      hb, w2b, prefix, tilemap, lists, pslot, nullptr, o2);

  combine_kernel<<<N_TOK * DM / 4 / 256, 256, 0, stream>>>(o2, out);
}